// Round 2
// baseline (253.476 us; speedup 1.0000x reference)
//
#include <hip/hip_runtime.h>

// CustomConv2d: 3x3 conv, stride 1, pad 1. B=32, Cin=128, H=W=56, Cout=256.
// Reference dtypes are fp32; round-1 NaN indicates inputs really are fp32
// (reading fp32 words as bf16 pairs yields NaN encodings). To be robust we
// SELF-DETECT the dtype on device: low 16 bits of fp32 words are random
// mantissa bits (~19% plausible bf16 exponents) vs ~100% for true bf16 data.
// Flag lives in d_ws; all downstream kernels branch uniformly on it.
//
// Compute path (dtype-independent): implicit GEMM, internally bf16.
//  M=cout(256), N=b*h*w(100352), K=cin*9(1152).
//  wt_repack: weight (256,128,3,3) -> wt[9][256][128] bf16 (k=cin contiguous)
//  x_repack : x NCHW -> xp padded NHWC [32][58][58][128] bf16 (zero border)
//  conv_mfma: 128x128 tile, BK=32, 36 K-steps, global_load_lds width=16,
//             16x16x32 bf16 MFMA, acc[4][4]/wave, XOR-swizzled LDS chunks.

typedef __attribute__((ext_vector_type(8))) short short8;
typedef __attribute__((ext_vector_type(4))) float floatx4;

typedef __attribute__((address_space(1))) const void* gas_ptr;
typedef __attribute__((address_space(3))) void* las_ptr;

__device__ static inline void gl2lds16(const void* g, void* l) {
    __builtin_amdgcn_global_load_lds((gas_ptr)g, (las_ptr)l, 16, 0, 0);
}

__device__ static inline float bf2f(unsigned short u) {
    union { unsigned int i; float f; } x; x.i = ((unsigned int)u) << 16; return x.f;
}
__device__ static inline unsigned short f2bf(float f) {
    union { float f; unsigned int i; } x; x.f = f;
    unsigned int r = (x.i + 0x7FFFu + ((x.i >> 16) & 1u)) >> 16;  // RNE
    return (unsigned short)r;
}

// ---------------- dtype detector: flag=1 if x looks like bf16 --------------
__global__ void detect_dtype(const unsigned int* __restrict__ x,
                             unsigned int* __restrict__ flag) {
    int cnt = 0;
    for (int r = 0; r < 4; ++r) {
        unsigned int w = x[r * 64 + threadIdx.x];
        unsigned short lo = (unsigned short)(w & 0xFFFFu);
        int e = (lo >> 7) & 0xFF;
        bool plaus = (lo == 0) || (e >= 96 && e <= 144);
        unsigned long long b = __ballot(plaus);
        if (threadIdx.x == 0) cnt += (int)__popcll(b);
    }
    if (threadIdx.x == 0) *flag = (cnt >= 205) ? 1u : 0u;  // >=80% of 256
}

// ---------------- weight repack -> [9][256][128] bf16 ----------------------
__global__ void wt_repack(const void* __restrict__ wsrc,
                          unsigned short* __restrict__ wt,
                          const unsigned int* __restrict__ flag) {
    const bool isbf = (*flag != 0);
    int idx = blockIdx.x * 256 + threadIdx.x;       // 294912 total, grid=1152
    int ci  = idx & 127;
    int co  = (idx >> 7) & 255;
    int off = idx >> 15;                            // 0..8 = dh*3+dw
    size_t s = (size_t)(co * 128 + ci) * 9 + off;
    float v = isbf ? bf2f(((const unsigned short*)wsrc)[s])
                   : ((const float*)wsrc)[s];
    wt[idx] = f2bf(v);
}

// ---------------- x NCHW -> padded NHWC bf16 [32][58][58][128] -------------
__global__ void x_repack(const void* __restrict__ xsrc,
                         unsigned short* __restrict__ xp,
                         const unsigned int* __restrict__ flag) {
    const bool isbf = (*flag != 0);
    int bh  = blockIdx.x;                 // 32*58 blocks
    int b   = bh / 58, hp = bh - b * 58;  // hp in [0,58)
    int tid = threadIdx.x;
    unsigned short* row = xp + (size_t)(b * 58 + hp) * 58 * 128;
    uint4 z; z.x = z.y = z.z = z.w = 0u;
    if (hp == 0 || hp == 57) {            // top/bottom pad rows: 928 uint4
        uint4* r = (uint4*)row;
        for (int t = tid; t < 928; t += 256) r[t] = z;
        return;
    }
    int h = hp - 1;
    if (tid < 16)      ((uint4*)row)[tid] = z;                    // w'=0 pad
    else if (tid < 32) ((uint4*)(row + 57 * 128))[tid - 16] = z;  // w'=57 pad
    const size_t base = (size_t)b * 128 * 3136 + (size_t)h * 56;
    for (int t = tid; t < 896; t += 256) {     // work item (cin-chunk c, w)
        int c = t / 56, w = t - c * 56;
        union { unsigned short s[8]; uint4 v; } pk;
#pragma unroll
        for (int j = 0; j < 8; ++j) {
            size_t idx = base + (size_t)(c * 8 + j) * 3136 + w;
            float v = isbf ? bf2f(((const unsigned short*)xsrc)[idx])
                           : ((const float*)xsrc)[idx];
            pk.s[j] = f2bf(v);
        }
        *(uint4*)(row + (w + 1) * 128 + c * 8) = pk.v;
    }
}

// ---------------- main: implicit-GEMM MFMA conv ----------------------------
__global__ __launch_bounds__(256) void conv_mfma(
    const unsigned short* __restrict__ xp,   // [32][58][58][128] bf16
    const unsigned short* __restrict__ wt,   // [9][256][128] bf16
    const void* __restrict__ bias,           // [256] fp32 or bf16
    void* __restrict__ out,                  // [32][256][56][56] fp32 or bf16
    const unsigned int* __restrict__ flag)
{
    __shared__ __align__(16) char lds[16384];   // A tile 8KB @0, B tile 8KB @8192
    const bool isbf = (*flag != 0);
    const int tid   = threadIdx.x;
    const int lane  = tid & 63;
    const int wv    = tid >> 6;        // wave 0..3
    const int ntile = blockIdx.x;      // 0..783 (spatial)
    const int mtile = blockIdx.y;      // 0..1   (cout)

    // ---- staging roles: thread covers rows r0 (issue0) and r1 (issue1),
    //      physical 16B chunk p of a 64B row; global chunk is XOR-swizzled.
    const int p  = lane & 3;
    const int r0 = wv * 16 + (lane >> 2);   // rows 0..63
    const int r1 = r0 + 64;                 // rows 64..127
    const int c0 = p ^ ((r0 >> 1) & 3);
    const int c1 = p ^ ((r1 >> 1) & 3);

    const unsigned short* a0 = wt + (mtile * 128 + r0) * 128 + c0 * 8;
    const unsigned short* a1 = wt + (mtile * 128 + r1) * 128 + c1 * 8;

    const int n0 = ntile * 128 + r0;
    const int n1 = ntile * 128 + r1;
    const int b0 = n0 / 3136, s0 = n0 - b0 * 3136;
    const int h0 = s0 / 56,   w0 = s0 - h0 * 56;
    const int b1 = n1 / 3136, s1 = n1 - b1 * 3136;
    const int h1 = s1 / 56,   w1 = s1 - h1 * 56;
    const unsigned short* bp0 = xp + ((size_t)(b0 * 58 + h0) * 58 + w0) * 128 + c0 * 8;
    const unsigned short* bp1 = xp + ((size_t)(b1 * 58 + h1) * 58 + w1) * 128 + c1 * 8;

    char* ldsA0 = lds + wv * 1024;
    char* ldsA1 = lds + (wv + 4) * 1024;
    char* ldsB0 = lds + 8192 + wv * 1024;
    char* ldsB1 = lds + 8192 + (wv + 4) * 1024;

    // ---- fragment-read geometry
    const int mbase = (wv >> 1) * 64 + (lane & 15);      // row in A tile
    const int nbase = (wv & 1) * 64 + (lane & 15);       // row in B tile
    const int ph    = (lane >> 4) ^ (((lane & 15) >> 1) & 3);  // physical chunk
    const char* la = lds;
    const char* lb = lds + 8192;

    floatx4 acc[4][4] = {};

    for (int step = 0; step < 36; ++step) {
        const int off = step >> 2;            // 0..8  (dh*3+dw)
        const int kb  = (step & 3) << 5;      // cin base 0/32/64/96
        const int dh  = off / 3, dw = off - dh * 3;
        const int aoff = off * 32768 + kb;
        const int boff = (dh * 58 + dw) * 128 + kb;
        gl2lds16(a0 + aoff, ldsA0);
        gl2lds16(a1 + aoff, ldsA1);
        gl2lds16(bp0 + boff, ldsB0);
        gl2lds16(bp1 + boff, ldsB1);
        __syncthreads();                      // drains vmcnt before barrier

        short8 af[4], bf[4];
#pragma unroll
        for (int t = 0; t < 4; ++t) {
            af[t] = *(const short8*)(la + (mbase + t * 16) * 64 + ph * 16);
            bf[t] = *(const short8*)(lb + (nbase + t * 16) * 64 + ph * 16);
        }
#pragma unroll
        for (int i = 0; i < 4; ++i)
#pragma unroll
            for (int j = 0; j < 4; ++j)
                acc[i][j] = __builtin_amdgcn_mfma_f32_16x16x32_bf16(
                    af[i], bf[j], acc[i][j], 0, 0, 0);
        __syncthreads();                      // protect LDS before next stage
    }

    // ---- epilogue: D[row=cout(quad*4+reg)][col=spatial(lane&15)]
    const int q = lane >> 4;
#pragma unroll
    for (int j = 0; j < 4; ++j) {
        const int n = ntile * 128 + (wv & 1) * 64 + j * 16 + (lane & 15);
        const int b = n / 3136;
        const int s = n - b * 3136;
#pragma unroll
        for (int i = 0; i < 4; ++i) {
            const int co = mtile * 128 + (wv >> 1) * 64 + i * 16 + q * 4;
            float bv[4];
            if (isbf) {
                const ushort4 bb = *(const ushort4*)((const unsigned short*)bias + co);
                bv[0] = bf2f(bb.x); bv[1] = bf2f(bb.y);
                bv[2] = bf2f(bb.z); bv[3] = bf2f(bb.w);
            } else {
                const float4 bb = *(const float4*)((const float*)bias + co);
                bv[0] = bb.x; bv[1] = bb.y; bv[2] = bb.z; bv[3] = bb.w;
            }
#pragma unroll
            for (int r = 0; r < 4; ++r) {
                const float v = acc[i][j][r] + bv[r];
                const size_t o = (size_t)b * 802816 + (size_t)(co + r) * 3136 + s;
                if (isbf) ((unsigned short*)out)[o] = f2bf(v);
                else      ((float*)out)[o] = v;
            }
        }
    }
}

// ---------------- fallback: naive direct conv fp32 (if ws too small) -------
__global__ void conv_naive(const float* __restrict__ x,
                           const float* __restrict__ w,
                           const float* __restrict__ bias,
                           float* __restrict__ out) {
    long long i = (long long)blockIdx.x * 256 + threadIdx.x;
    if (i >= 25690112LL) return;
    int wo = (int)(i % 56); long long t = i / 56;
    int ho = (int)(t % 56); t /= 56;
    int co = (int)(t % 256); int b = (int)(t / 256);
    float acc = bias[co];
    for (int ci = 0; ci < 128; ++ci)
        for (int dh = 0; dh < 3; ++dh) {
            int hi = ho + dh - 1; if ((unsigned)hi >= 56u) continue;
            for (int dw = 0; dw < 3; ++dw) {
                int wi = wo + dw - 1; if ((unsigned)wi >= 56u) continue;
                acc += x[((size_t)(b * 128 + ci) * 56 + hi) * 56 + wi] *
                       w[((co * 128 + ci) * 3 + dh) * 3 + dw];
            }
        }
    out[i] = acc;
}

extern "C" void kernel_launch(void* const* d_in, const int* in_sizes, int n_in,
                              void* d_out, int out_size, void* d_ws, size_t ws_size,
                              hipStream_t stream) {
    const void* x    = d_in[0];
    const void* w    = d_in[1];
    const void* bias = d_in[2];
    // d_in[3] = approximate (scalar, does not affect exact math) — unused.

    const size_t xp_bytes = (size_t)32 * 58 * 58 * 128 * 2;   // 27,557,888
    const size_t wt_off   = xp_bytes;
    const size_t wt_bytes = (size_t)9 * 256 * 128 * 2;        // 589,824
    const size_t fl_off   = wt_off + wt_bytes;                // 4B aligned
    const size_t need     = fl_off + 64;

    if (ws_size >= need) {
        unsigned short* xp = (unsigned short*)d_ws;
        unsigned short* wt = (unsigned short*)((char*)d_ws + wt_off);
        unsigned int* flag = (unsigned int*)((char*)d_ws + fl_off);
        detect_dtype<<<1, 64, 0, stream>>>((const unsigned int*)x, flag);
        x_repack<<<32 * 58, 256, 0, stream>>>(x, xp, flag);
        wt_repack<<<1152, 256, 0, stream>>>(w, wt, flag);
        dim3 grid(784, 2, 1);
        conv_mfma<<<grid, 256, 0, stream>>>(xp, wt, bias, d_out, flag);
    } else {
        conv_naive<<<(25690112 + 255) / 256, 256, 0, stream>>>(
            (const float*)x, (const float*)w, (const float*)bias, (float*)d_out);
    }
}

// Round 3
// 232.468 us; speedup vs baseline: 1.0904x; 1.0904x over previous
//
#include <hip/hip_runtime.h>

// CustomConv2d: 3x3 conv, stride 1, pad 1. B=32, Cin=128, H=W=56, Cout=256.
// Inputs are fp32 (round-1 NaN proved it) but we keep the device-side dtype
// self-detector for robustness; flag in d_ws, uniform branch downstream.
//
// Implicit GEMM, internally bf16. M=cout(256), N=b*h*w(100352), K=cin*9(1152).
//  wt_repack: weight (256,128,3,3) -> wt[9][256][128] bf16 (k=cin contiguous)
//  x_repack : NCHW -> padded NHWC [32][58][58][128] bf16 via LDS transpose
//             (coalesced reads AND writes; round-2's version had 256B-stride
//              scattered writes -> ~120us; this one targets ~15us)
//  conv_mfma: 128x128 tile, BK=64 (32KB LDS, 32 MFMA/barrier, 18 steps),
//             global_load_lds width=16, 16x16x32 bf16 MFMA, acc[4][4]/wave,
//             row-XOR chunk swizzle for conflict-free ds_read_b128.

typedef __attribute__((ext_vector_type(8))) short short8;
typedef __attribute__((ext_vector_type(4))) float floatx4;

typedef __attribute__((address_space(1))) const void* gas_ptr;
typedef __attribute__((address_space(3))) void* las_ptr;

__device__ static inline void gl2lds16(const void* g, void* l) {
    __builtin_amdgcn_global_load_lds((gas_ptr)g, (las_ptr)l, 16, 0, 0);
}

__device__ static inline float bf2f(unsigned short u) {
    union { unsigned int i; float f; } x; x.i = ((unsigned int)u) << 16; return x.f;
}
__device__ static inline unsigned short f2bf(float f) {
    union { float f; unsigned int i; } x; x.f = f;
    unsigned int r = (x.i + 0x7FFFu + ((x.i >> 16) & 1u)) >> 16;  // RNE
    return (unsigned short)r;
}

// ---------------- dtype detector: flag=1 if x looks like bf16 --------------
__global__ void detect_dtype(const unsigned int* __restrict__ x,
                             unsigned int* __restrict__ flag) {
    int cnt = 0;
    for (int r = 0; r < 4; ++r) {
        unsigned int w = x[r * 64 + threadIdx.x];
        unsigned short lo = (unsigned short)(w & 0xFFFFu);
        int e = (lo >> 7) & 0xFF;
        bool plaus = (lo == 0) || (e >= 96 && e <= 144);
        unsigned long long b = __ballot(plaus);
        if (threadIdx.x == 0) cnt += (int)__popcll(b);
    }
    if (threadIdx.x == 0) *flag = (cnt >= 205) ? 1u : 0u;  // >=80% of 256
}

// ---------------- weight repack -> [9][256][128] bf16 ----------------------
__global__ void wt_repack(const void* __restrict__ wsrc,
                          unsigned short* __restrict__ wt,
                          const unsigned int* __restrict__ flag) {
    const bool isbf = (*flag != 0);
    int idx = blockIdx.x * 256 + threadIdx.x;       // 294912 total, grid=1152
    int ci  = idx & 127;
    int co  = (idx >> 7) & 255;
    int off = idx >> 15;                            // 0..8 = dh*3+dw
    size_t s = (size_t)(co * 128 + ci) * 9 + off;
    float v = isbf ? bf2f(((const unsigned short*)wsrc)[s])
                   : ((const float*)wsrc)[s];
    wt[idx] = f2bf(v);
}

// ------- x NCHW -> padded NHWC bf16 [32][58][58][128], LDS transpose -------
__global__ __launch_bounds__(256) void x_repack(
    const void* __restrict__ xsrc, unsigned short* __restrict__ xp,
    const unsigned int* __restrict__ flag) {
    __shared__ unsigned short tile[56 * 130];   // pad 130: conflict-free
    const bool isbf = (*flag != 0);
    const int bh  = blockIdx.x;                 // 32*58 blocks
    const int b   = bh / 58, hp = bh - b * 58;  // hp in [0,58)
    const int tid = threadIdx.x;
    unsigned short* row = xp + (size_t)(b * 58 + hp) * 58 * 128;
    if (hp == 0 || hp == 57) {                  // top/bottom pad rows
        uint4 z; z.x = z.y = z.z = z.w = 0u;
        uint4* r = (uint4*)row;
        for (int t = tid; t < 928; t += 256) r[t] = z;
        return;
    }
    const int h = hp - 1;
    // phase 1: coalesced vector reads, transposed bf16 stores into LDS
    if (isbf) {
        const unsigned short* xs =
            (const unsigned short*)xsrc + (size_t)b * 128 * 3136 + h * 56;
#pragma unroll
        for (int it = 0; it < 7; ++it) {        // 1792 items = 128ci x 14 w4
            int idx = it * 256 + tid;
            int ci = idx / 14, w4 = idx - ci * 14;
            ushort4 v = *(const ushort4*)(xs + (size_t)ci * 3136 + w4 * 4);
            tile[(w4 * 4 + 0) * 130 + ci] = v.x;
            tile[(w4 * 4 + 1) * 130 + ci] = v.y;
            tile[(w4 * 4 + 2) * 130 + ci] = v.z;
            tile[(w4 * 4 + 3) * 130 + ci] = v.w;
        }
    } else {
        const float* xs = (const float*)xsrc + (size_t)b * 128 * 3136 + h * 56;
#pragma unroll
        for (int it = 0; it < 7; ++it) {
            int idx = it * 256 + tid;
            int ci = idx / 14, w4 = idx - ci * 14;
            float4 v = *(const float4*)(xs + (size_t)ci * 3136 + w4 * 4);
            tile[(w4 * 4 + 0) * 130 + ci] = f2bf(v.x);
            tile[(w4 * 4 + 1) * 130 + ci] = f2bf(v.y);
            tile[(w4 * 4 + 2) * 130 + ci] = f2bf(v.z);
            tile[(w4 * 4 + 3) * 130 + ci] = f2bf(v.w);
        }
    }
    __syncthreads();
    // phase 2: fully-coalesced uint4 writes of the NHWC row (incl. W pads)
#pragma unroll
    for (int it = 0; it < 4; ++it) {
        int k = it * 256 + tid;                 // 928 chunks of 16B
        if (k >= 928) break;
        int wq = k >> 4, cc = k & 15;
        uint4 v;
        if (wq == 0 || wq == 57) { v.x = v.y = v.z = v.w = 0u; }
        else {
            const unsigned short* p = &tile[(wq - 1) * 130 + cc * 8];
            union { unsigned short s[8]; uint4 u; } pk;
#pragma unroll
            for (int j = 0; j < 8; ++j) pk.s[j] = p[j];
            v = pk.u;
        }
        *(uint4*)(row + wq * 128 + cc * 8) = v;
    }
}

// ---------------- main: implicit-GEMM MFMA conv, BK=64 ---------------------
__global__ __launch_bounds__(256) void conv_mfma(
    const unsigned short* __restrict__ xp,   // [32][58][58][128] bf16
    const unsigned short* __restrict__ wt,   // [9][256][128] bf16
    const void* __restrict__ bias,           // [256] fp32 or bf16
    void* __restrict__ out,                  // [32][256][56][56] fp32 or bf16
    const unsigned int* __restrict__ flag)
{
    __shared__ __align__(16) char lds[32768];   // A 16KB @0, B 16KB @16384
    const bool isbf = (*flag != 0);
    const int tid   = threadIdx.x;
    const int lane  = tid & 63;
    const int wv    = tid >> 6;        // wave 0..3
    const int ntile = blockIdx.x;      // 0..783 (spatial)
    const int mtile = blockIdx.y;      // 0..1   (cout)

    // ---- staging geometry: slot s = i*256 + wv*64 + lane (i = 0..3),
    //      row = s>>3 = i*32 + srow, phys chunk = lane&7, XOR row-swizzled.
    const int srow  = wv * 8 + (lane >> 3);
    const int cphys = lane & 7;
    const int clog  = cphys ^ (srow & 7);   // row&7 independent of i

    const unsigned short* aBase = wt + (mtile * 128 + srow) * 128 + clog * 8;

    size_t bOff[4];
#pragma unroll
    for (int i = 0; i < 4; ++i) {
        const int n = ntile * 128 + i * 32 + srow;
        const int b = n / 3136, s = n - b * 3136;
        const int h = s / 56,   w = s - h * 56;
        bOff[i] = ((size_t)(b * 58 + h) * 58 + w) * 128 + clog * 8;
    }

    // ---- fragment-read geometry
    const int mbase = (wv >> 1) * 64 + (lane & 15);      // row in A tile
    const int nbase = (wv & 1) * 64 + (lane & 15);       // row in B tile
    const int q     = lane >> 4;
    const int rx    = lane & 7;                          // row&7 for frag rows
    const char* la = lds;
    const char* lb = lds + 16384;

    floatx4 acc[4][4] = {};

    for (int step = 0; step < 18; ++step) {
        const int off = step >> 1;            // 0..8  (dh*3+dw)
        const int kb  = (step & 1) << 6;      // cin base 0 / 64
        const int dh  = off / 3, dw = off - dh * 3;
        const int aoff = off * 32768 + kb;
        const size_t boff = (size_t)(dh * 58 + dw) * 128 + kb;
#pragma unroll
        for (int i = 0; i < 4; ++i) {
            gl2lds16(aBase + i * 4096 + aoff, lds + i * 4096 + wv * 1024);
            gl2lds16(xp + bOff[i] + boff, lds + 16384 + i * 4096 + wv * 1024);
        }
        __syncthreads();                      // drains vmcnt before barrier

#pragma unroll
        for (int s = 0; s < 2; ++s) {
            const int pc = ((s * 4 + q) ^ rx) * 16;   // phys chunk byte off
            short8 af[4], bfr[4];
#pragma unroll
            for (int t = 0; t < 4; ++t) {
                af[t]  = *(const short8*)(la + (mbase + t * 16) * 128 + pc);
                bfr[t] = *(const short8*)(lb + (nbase + t * 16) * 128 + pc);
            }
#pragma unroll
            for (int i = 0; i < 4; ++i)
#pragma unroll
                for (int j = 0; j < 4; ++j)
                    acc[i][j] = __builtin_amdgcn_mfma_f32_16x16x32_bf16(
                        af[i], bfr[j], acc[i][j], 0, 0, 0);
        }
        __syncthreads();                      // protect LDS before next stage
    }

    // ---- epilogue: D[row=cout(quad*4+reg)][col=spatial(lane&15)]
#pragma unroll
    for (int j = 0; j < 4; ++j) {
        const int n = ntile * 128 + (wv & 1) * 64 + j * 16 + (lane & 15);
        const int b = n / 3136;
        const int s = n - b * 3136;
#pragma unroll
        for (int i = 0; i < 4; ++i) {
            const int co = mtile * 128 + (wv >> 1) * 64 + i * 16 + q * 4;
            float bv[4];
            if (isbf) {
                const ushort4 bb = *(const ushort4*)((const unsigned short*)bias + co);
                bv[0] = bf2f(bb.x); bv[1] = bf2f(bb.y);
                bv[2] = bf2f(bb.z); bv[3] = bf2f(bb.w);
            } else {
                const float4 bb = *(const float4*)((const float*)bias + co);
                bv[0] = bb.x; bv[1] = bb.y; bv[2] = bb.z; bv[3] = bb.w;
            }
#pragma unroll
            for (int r = 0; r < 4; ++r) {
                const float v = acc[i][j][r] + bv[r];
                const size_t o = (size_t)b * 802816 + (size_t)(co + r) * 3136 + s;
                if (isbf) ((unsigned short*)out)[o] = f2bf(v);
                else      ((float*)out)[o] = v;
            }
        }
    }
}

// ---------------- fallback: naive direct conv fp32 (if ws too small) -------
__global__ void conv_naive(const float* __restrict__ x,
                           const float* __restrict__ w,
                           const float* __restrict__ bias,
                           float* __restrict__ out) {
    long long i = (long long)blockIdx.x * 256 + threadIdx.x;
    if (i >= 25690112LL) return;
    int wo = (int)(i % 56); long long t = i / 56;
    int ho = (int)(t % 56); t /= 56;
    int co = (int)(t % 256); int b = (int)(t / 256);
    float acc = bias[co];
    for (int ci = 0; ci < 128; ++ci)
        for (int dh = 0; dh < 3; ++dh) {
            int hi = ho + dh - 1; if ((unsigned)hi >= 56u) continue;
            for (int dw = 0; dw < 3; ++dw) {
                int wi = wo + dw - 1; if ((unsigned)wi >= 56u) continue;
                acc += x[((size_t)(b * 128 + ci) * 56 + hi) * 56 + wi] *
                       w[((co * 128 + ci) * 3 + dh) * 3 + dw];
            }
        }
    out[i] = acc;
}

extern "C" void kernel_launch(void* const* d_in, const int* in_sizes, int n_in,
                              void* d_out, int out_size, void* d_ws, size_t ws_size,
                              hipStream_t stream) {
    const void* x    = d_in[0];
    const void* w    = d_in[1];
    const void* bias = d_in[2];
    // d_in[3] = approximate (scalar, does not affect exact math) — unused.

    const size_t xp_bytes = (size_t)32 * 58 * 58 * 128 * 2;   // 27,557,888
    const size_t wt_off   = xp_bytes;
    const size_t wt_bytes = (size_t)9 * 256 * 128 * 2;        // 589,824
    const size_t fl_off   = wt_off + wt_bytes;                // 4B aligned
    const size_t need     = fl_off + 64;

    if (ws_size >= need) {
        unsigned short* xp = (unsigned short*)d_ws;
        unsigned short* wt = (unsigned short*)((char*)d_ws + wt_off);
        unsigned int* flag = (unsigned int*)((char*)d_ws + fl_off);
        detect_dtype<<<1, 64, 0, stream>>>((const unsigned int*)x, flag);
        x_repack<<<32 * 58, 256, 0, stream>>>(x, xp, flag);
        wt_repack<<<1152, 256, 0, stream>>>(w, wt, flag);
        dim3 grid(784, 2, 1);
        conv_mfma<<<grid, 256, 0, stream>>>(xp, wt, bias, d_out, flag);
    } else {
        conv_naive<<<(25690112 + 255) / 256, 256, 0, stream>>>(
            (const float*)x, (const float*)w, (const float*)bias, (float*)d_out);
    }
}